// Round 9
// baseline (91.716 us; speedup 1.0000x reference)
//
#include <hip/hip_runtime.h>
#include <math.h>

// Barrier_Net: deep-sets net + barrier + global max-rescale.
// R6 WIN: removed same-address atomic storm. R7 WIN (89.8us): fused per-row
// pipeline, 2 dispatches. R8 FAILED: 2-rows/block + 32 waves/CU regressed
// (+1.9us) => bn_row is VALU-ISSUE bound near its scalar floor, not latency.
// R9: R7 structure EXACTLY, but phase 1 (60% of VALU) packed as float2
// ext-vectors -> v_pk_fma_f32 / v_pk_max_f32. Clean A/B for whether gfx950
// runs packed fp32 at full rate (2x FLOP/issue, CDNA3-style) or
// double-pumped (neutral). Identical per-element fp32 ops.

#define NBLK 1024   // 4 rows/block (wave <-> row), 4096 rows

typedef float v2f __attribute__((ext_vector_type(2)));

__global__ __launch_bounds__(256, 4) void bn_row(
    const float* __restrict__ x,
    const float* __restrict__ w1,  const float* __restrict__ b1,
    const float* __restrict__ w2,  const float* __restrict__ b2,
    const float* __restrict__ rw1, const float* __restrict__ rb1,
    const float* __restrict__ rw2, const float* __restrict__ rb2,
    float* __restrict__ out, float* __restrict__ blkmax)
{
    __shared__ __align__(16) float sx[4][268];   // per-wave row buffer
    __shared__ __align__(16) float sH[4][264];   // per-row summed hidden
    __shared__ float sXp[4][4][68];              // [k-quarter][row][o]
    __shared__ __align__(16) float sX[4][68];    // per-row phi-sum
    __shared__ float sP4[4][4][2];               // [wave][row][c]
    __shared__ float sbar[4][2];
    __shared__ float sa[8];

    const int tid = threadIdx.x;
    const int ln  = tid & 63;
    const int wv  = tid >> 6;
    const int b0  = blockIdx.x * 4;
    const int row = b0 + wv;                     // wave <-> batch row
    const float4* __restrict__ x4 = (const float4*)(x + (size_t)row * 264);

    // Two coalesced loads cover the whole row; stage into this wave's buffer.
    float4 xr = x4[ln];          // neighbor block n = ln
    float4 pv = x4[ln + 2];      // neighbor block n = ln+2 (also barrier data)
    ((float4*)sx[wv])[ln] = xr;
    if (ln >= 62) ((float4*)sx[wv])[ln + 2] = pv;   // slots 64, 65

    // ---- phase 1 (PACKED): lane ln owns hidden units 4ln..4ln+3 as 2 pairs --
    float4 w1r0 = ((const float4*)(w1      ))[ln];
    float4 w1r1 = ((const float4*)(w1 + 256))[ln];
    float4 w1r2 = ((const float4*)(w1 + 512))[ln];
    float4 w1r3 = ((const float4*)(w1 + 768))[ln];
    float4 b1r  = ((const float4*)b1)[ln];

    // natural adjacent pairs: pair0 = units (4ln,4ln+1), pair1 = (4ln+2,4ln+3)
    v2f wp00 = {w1r0.x, w1r0.y}, wp01 = {w1r0.z, w1r0.w};
    v2f wp10 = {w1r1.x, w1r1.y}, wp11 = {w1r1.z, w1r1.w};
    v2f wp20 = {w1r2.x, w1r2.y}, wp21 = {w1r2.z, w1r2.w};
    v2f wp30 = {w1r3.x, w1r3.y}, wp31 = {w1r3.z, w1r3.w};
    v2f bp0  = {b1r.x, b1r.y},   bp1  = {b1r.z, b1r.w};
    const v2f vzero = {0.f, 0.f};

    v2f ap0 = vzero, ap1 = vzero;
    #pragma unroll 4
    for (int n = 0; n < 66; n++) {
        float4 xv = ((const float4*)sx[wv])[n];   // uniform b128 broadcast
        v2f xx0 = {xv.x, xv.x}, xx1 = {xv.y, xv.y};
        v2f xx2 = {xv.z, xv.z}, xx3 = {xv.w, xv.w};
        v2f h0 = __builtin_elementwise_fma(xx0, wp00, bp0);
        h0 = __builtin_elementwise_fma(xx1, wp10, h0);
        h0 = __builtin_elementwise_fma(xx2, wp20, h0);
        h0 = __builtin_elementwise_fma(xx3, wp30, h0);
        v2f h1 = __builtin_elementwise_fma(xx0, wp01, bp1);
        h1 = __builtin_elementwise_fma(xx1, wp11, h1);
        h1 = __builtin_elementwise_fma(xx2, wp21, h1);
        h1 = __builtin_elementwise_fma(xx3, wp31, h1);
        ap0 += __builtin_elementwise_max(h0, vzero);
        ap1 += __builtin_elementwise_max(h1, vzero);
    }
    ((float4*)sH[wv])[ln] = make_float4(ap0.x, ap0.y, ap1.x, ap1.y);

    // barrier term: lane ln <-> neighbor n = ln+2 (exactly 64 neighbors)
    {
        float px = pv.x, py = pv.y;
        float d  = sqrtf(px * px + py * py);
        float t  = d - 0.15f;
        float inv = 1.0f / (t * t);
        float bx = -px * inv, by = -py * inv;
        #pragma unroll
        for (int m = 32; m >= 1; m >>= 1) {
            bx += __shfl_xor(bx, m);
            by += __shfl_xor(by, m);
        }
        if (ln == 0) { sbar[wv][0] = bx; sbar[wv][1] = by; }
    }
    __syncthreads();

    // ---- phase 2: X[r][o] = sum_k H[r][k] w2[k][o] + 66 b2[o] ----
    // wave wv owns k-quarter [64wv,64wv+64); lane = o.
    {
        float xp0 = 0.f, xp1 = 0.f, xp2 = 0.f, xp3 = 0.f;
        const float* w2q = w2 + (wv << 12);
        #pragma unroll 2
        for (int i = 0; i < 16; i++) {
            int kb = (wv << 4) + i;
            float4 h0 = ((const float4*)sH[0])[kb];
            float4 h1 = ((const float4*)sH[1])[kb];
            float4 h2 = ((const float4*)sH[2])[kb];
            float4 h3 = ((const float4*)sH[3])[kb];
            float wk0 = w2q[(((i << 2) + 0) << 6) + ln];
            float wk1 = w2q[(((i << 2) + 1) << 6) + ln];
            float wk2 = w2q[(((i << 2) + 2) << 6) + ln];
            float wk3 = w2q[(((i << 2) + 3) << 6) + ln];
            xp0 = fmaf(h0.x, wk0, xp0); xp1 = fmaf(h1.x, wk0, xp1);
            xp2 = fmaf(h2.x, wk0, xp2); xp3 = fmaf(h3.x, wk0, xp3);
            xp0 = fmaf(h0.y, wk1, xp0); xp1 = fmaf(h1.y, wk1, xp1);
            xp2 = fmaf(h2.y, wk1, xp2); xp3 = fmaf(h3.y, wk1, xp3);
            xp0 = fmaf(h0.z, wk2, xp0); xp1 = fmaf(h1.z, wk2, xp1);
            xp2 = fmaf(h2.z, wk2, xp2); xp3 = fmaf(h3.z, wk2, xp3);
            xp0 = fmaf(h0.w, wk3, xp0); xp1 = fmaf(h1.w, wk3, xp1);
            xp2 = fmaf(h2.w, wk3, xp2); xp3 = fmaf(h3.w, wk3, xp3);
        }
        sXp[wv][0][ln] = xp0; sXp[wv][1][ln] = xp1;
        sXp[wv][2][ln] = xp2; sXp[wv][3][ln] = xp3;
    }
    __syncthreads();

    {
        float Xf = sXp[0][wv][ln] + sXp[1][wv][ln]
                 + sXp[2][wv][ln] + sXp[3][wv][ln] + 66.0f * b2[ln];
        sX[wv][ln] = Xf;
    }
    __syncthreads();

    // ---- phase 3: h2[r][h] = relu(sum_o X[r][o] rw1[o][h] + rb1[h]) ----
    float c0, c1, c2, c3;
    c0 = c1 = c2 = c3 = rb1[tid];
    #pragma unroll 2
    for (int i = 0; i < 16; i++) {
        float4 X0 = ((const float4*)sX[0])[i];
        float4 X1 = ((const float4*)sX[1])[i];
        float4 X2 = ((const float4*)sX[2])[i];
        float4 X3 = ((const float4*)sX[3])[i];
        float r0 = rw1[(((i << 2) + 0) << 8) + tid];
        float r1 = rw1[(((i << 2) + 1) << 8) + tid];
        float r2 = rw1[(((i << 2) + 2) << 8) + tid];
        float r3 = rw1[(((i << 2) + 3) << 8) + tid];
        c0 = fmaf(X0.x, r0, c0); c1 = fmaf(X1.x, r0, c1);
        c2 = fmaf(X2.x, r0, c2); c3 = fmaf(X3.x, r0, c3);
        c0 = fmaf(X0.y, r1, c0); c1 = fmaf(X1.y, r1, c1);
        c2 = fmaf(X2.y, r1, c2); c3 = fmaf(X3.y, r1, c3);
        c0 = fmaf(X0.z, r2, c0); c1 = fmaf(X1.z, r2, c1);
        c2 = fmaf(X2.z, r2, c2); c3 = fmaf(X3.z, r2, c3);
        c0 = fmaf(X0.w, r3, c0); c1 = fmaf(X1.w, r3, c1);
        c2 = fmaf(X2.w, r3, c2); c3 = fmaf(X3.w, r3, c3);
    }
    c0 = fmaxf(c0, 0.f); c1 = fmaxf(c1, 0.f);
    c2 = fmaxf(c2, 0.f); c3 = fmaxf(c3, 0.f);

    // ---- phase 4: pre[r][c] = sum_h h2[r][h] rw2[h][c]; butterfly over h ----
    {
        float2 r2v = ((const float2*)rw2)[tid];
        float p00 = c0 * r2v.x, p01 = c0 * r2v.y;
        float p10 = c1 * r2v.x, p11 = c1 * r2v.y;
        float p20 = c2 * r2v.x, p21 = c2 * r2v.y;
        float p30 = c3 * r2v.x, p31 = c3 * r2v.y;
        #pragma unroll
        for (int m = 32; m >= 1; m >>= 1) {
            p00 += __shfl_xor(p00, m); p01 += __shfl_xor(p01, m);
            p10 += __shfl_xor(p10, m); p11 += __shfl_xor(p11, m);
            p20 += __shfl_xor(p20, m); p21 += __shfl_xor(p21, m);
            p30 += __shfl_xor(p30, m); p31 += __shfl_xor(p31, m);
        }
        if (ln == 0) {
            sP4[wv][0][0] = p00; sP4[wv][0][1] = p01;
            sP4[wv][1][0] = p10; sP4[wv][1][1] = p11;
            sP4[wv][2][0] = p20; sP4[wv][2][1] = p21;
            sP4[wv][3][0] = p30; sP4[wv][3][1] = p31;
        }
    }
    __syncthreads();

    if (tid < 8) {
        int r = tid >> 1, c = tid & 1;
        float pre = sP4[0][r][c] + sP4[1][r][c] + sP4[2][r][c] + sP4[3][r][c] + rb2[c];
        float a = 2.0f * tanhf(pre) + sbar[r][c];
        out[b0 * 2 + tid] = a;
        sa[tid] = a;
    }
    __syncthreads();
    // No global atomic: block max -> distinct slot (plain store).
    if (tid == 0) {
        float m = sa[0];
        #pragma unroll
        for (int i = 1; i < 8; i++) m = fmaxf(m, sa[i]);
        blkmax[blockIdx.x] = m;
    }
}

// ---- K2: reduce 1024 block maxima (L2-hot) + conditional rescale ----
__global__ __launch_bounds__(256) void bn_scale(
    float* __restrict__ out, const float* __restrict__ blkmax)
{
    __shared__ float sm[4];
    const int tid = threadIdx.x;
    const int ln  = tid & 63;
    const int wv  = tid >> 6;

    float m = fmaxf(fmaxf(blkmax[tid], blkmax[tid + 256]),
                    fmaxf(blkmax[tid + 512], blkmax[tid + 768]));
    #pragma unroll
    for (int s = 32; s >= 1; s >>= 1) m = fmaxf(m, __shfl_xor(m, s));
    if (ln == 0) sm[wv] = m;
    __syncthreads();
    float amax = fmaxf(fmaxf(sm[0], sm[1]), fmaxf(sm[2], sm[3]));

    float scale = 2.0f / amax;
    int i = blockIdx.x * 256 + tid;
    float a = out[i];
    out[i] = (scale < 1.0f) ? a * scale : a;
}

extern "C" void kernel_launch(void* const* d_in, const int* in_sizes, int n_in,
                              void* d_out, int out_size, void* d_ws, size_t ws_size,
                              hipStream_t stream) {
    const float* x   = (const float*)d_in[0];
    const float* w1  = (const float*)d_in[1];
    const float* b1  = (const float*)d_in[2];
    const float* w2  = (const float*)d_in[3];
    const float* b2  = (const float*)d_in[4];
    const float* rw1 = (const float*)d_in[5];
    const float* rb1 = (const float*)d_in[6];
    const float* rw2 = (const float*)d_in[7];
    const float* rb2 = (const float*)d_in[8];
    float* out = (float*)d_out;
    float* blkmax = (float*)d_ws;   // 1024 distinct slots, no init needed

    bn_row<<<NBLK, 256, 0, stream>>>(x, w1, b1, w2, b2, rw1, rb1, rw2, rb2,
                                     out, blkmax);
    bn_scale<<<8192 / 256, 256, 0, stream>>>(out, blkmax);
}

// Round 10
// 91.160 us; speedup vs baseline: 1.0061x; 1.0061x over previous
//
#include <hip/hip_runtime.h>
#include <math.h>

// Barrier_Net: deep-sets net + barrier + global max-rescale. FINAL (R7 config).
//
// Session summary (MI355X, total timed window incl. ~60us fixed harness cost:
// 256MiB ws-poison fill = 41us @ 84% HBM peak, out-poison, input restores,
// graph gaps):
//   R1 103.8  baseline fused-LDS version (LDS-broadcast storm in phase 1)
//   R2  98.7  s_load x path            (neutral: moved sink to scalar-mem)
//   R3 102.3  readlane x path          (neutral)
//   R4 115.9  full unroll + 1-dispatch (FAILED: +2nd same-addr atomic)
//   R5 104.1  rolled loops, 3 kernels  (neutral)
//   R6  95.2  WIN: removed same-address device atomicMax storm (-9us)
//   R7  89.8  WIN: fused per-row pipeline, 2 dispatches, H in LDS (-5.5us)
//   R8  91.7  FAILED: 2 rows/block + 32 waves/CU (critical-path theory wrong)
//   R9  91.7  NEUTRAL: v_pk_fma_f32 double-pumped on gfx950 (no 2x fp32)
// bn_row is VALU-issue bound within ~20% of its scalar-issue floor (~9us);
// remaining total is harness-fixed. This file = R7 verbatim (best measured).

#define NBLK 1024   // 4 rows/block (wave <-> row), 4096 rows

__global__ __launch_bounds__(256, 4) void bn_row(
    const float* __restrict__ x,
    const float* __restrict__ w1,  const float* __restrict__ b1,
    const float* __restrict__ w2,  const float* __restrict__ b2,
    const float* __restrict__ rw1, const float* __restrict__ rb1,
    const float* __restrict__ rw2, const float* __restrict__ rb2,
    float* __restrict__ out, float* __restrict__ blkmax)
{
    __shared__ __align__(16) float sx[4][268];   // per-wave row buffer
    __shared__ __align__(16) float sH[4][264];   // per-row summed hidden
    __shared__ float sXp[4][4][68];              // [k-quarter][row][o]
    __shared__ __align__(16) float sX[4][68];    // per-row phi-sum
    __shared__ float sP4[4][4][2];               // [wave][row][c]
    __shared__ float sbar[4][2];
    __shared__ float sa[8];

    const int tid = threadIdx.x;
    const int ln  = tid & 63;
    const int wv  = tid >> 6;
    const int b0  = blockIdx.x * 4;
    const int row = b0 + wv;                     // wave <-> batch row
    const float4* __restrict__ x4 = (const float4*)(x + (size_t)row * 264);

    // Two coalesced loads cover the whole row; stage into this wave's buffer.
    float4 xr = x4[ln];          // neighbor block n = ln
    float4 pv = x4[ln + 2];      // neighbor block n = ln+2 (also barrier data)
    ((float4*)sx[wv])[ln] = xr;
    if (ln >= 62) ((float4*)sx[wv])[ln + 2] = pv;   // slots 64, 65

    // ---- phase 1: lane ln owns hidden units 4ln..4ln+3 ----
    float4 w1r0 = ((const float4*)(w1      ))[ln];
    float4 w1r1 = ((const float4*)(w1 + 256))[ln];
    float4 w1r2 = ((const float4*)(w1 + 512))[ln];
    float4 w1r3 = ((const float4*)(w1 + 768))[ln];
    float4 b1r  = ((const float4*)b1)[ln];

    float a0 = 0.f, a1 = 0.f, a2 = 0.f, a3 = 0.f;
    // Rolled loop; uniform-address ds_read_b128 = conflict-free broadcast.
    #pragma unroll 4
    for (int n = 0; n < 66; n++) {
        float4 xv = ((const float4*)sx[wv])[n];
        float h0 = b1r.x, h1 = b1r.y, h2 = b1r.z, h3 = b1r.w;
        h0 = fmaf(xv.x, w1r0.x, h0); h1 = fmaf(xv.x, w1r0.y, h1);
        h2 = fmaf(xv.x, w1r0.z, h2); h3 = fmaf(xv.x, w1r0.w, h3);
        h0 = fmaf(xv.y, w1r1.x, h0); h1 = fmaf(xv.y, w1r1.y, h1);
        h2 = fmaf(xv.y, w1r1.z, h2); h3 = fmaf(xv.y, w1r1.w, h3);
        h0 = fmaf(xv.z, w1r2.x, h0); h1 = fmaf(xv.z, w1r2.y, h1);
        h2 = fmaf(xv.z, w1r2.z, h2); h3 = fmaf(xv.z, w1r2.w, h3);
        h0 = fmaf(xv.w, w1r3.x, h0); h1 = fmaf(xv.w, w1r3.y, h1);
        h2 = fmaf(xv.w, w1r3.z, h2); h3 = fmaf(xv.w, w1r3.w, h3);
        a0 += fmaxf(h0, 0.f); a1 += fmaxf(h1, 0.f);
        a2 += fmaxf(h2, 0.f); a3 += fmaxf(h3, 0.f);
    }
    ((float4*)sH[wv])[ln] = make_float4(a0, a1, a2, a3);   // stays in LDS

    // barrier term: lane ln <-> neighbor n = ln+2 (exactly 64 neighbors)
    {
        float px = pv.x, py = pv.y;
        float d  = sqrtf(px * px + py * py);
        float t  = d - 0.15f;
        float inv = 1.0f / (t * t);
        float bx = -px * inv, by = -py * inv;
        #pragma unroll
        for (int m = 32; m >= 1; m >>= 1) {
            bx += __shfl_xor(bx, m);
            by += __shfl_xor(by, m);
        }
        if (ln == 0) { sbar[wv][0] = bx; sbar[wv][1] = by; }
    }
    __syncthreads();

    // ---- phase 2: X[r][o] = sum_k H[r][k] w2[k][o] + 66 b2[o] ----
    // wave wv owns k-quarter [64wv,64wv+64); lane = o.
    {
        float xp0 = 0.f, xp1 = 0.f, xp2 = 0.f, xp3 = 0.f;
        const float* w2q = w2 + (wv << 12);
        #pragma unroll 2
        for (int i = 0; i < 16; i++) {
            int kb = (wv << 4) + i;
            float4 h0 = ((const float4*)sH[0])[kb];
            float4 h1 = ((const float4*)sH[1])[kb];
            float4 h2 = ((const float4*)sH[2])[kb];
            float4 h3 = ((const float4*)sH[3])[kb];
            float wk0 = w2q[(((i << 2) + 0) << 6) + ln];
            float wk1 = w2q[(((i << 2) + 1) << 6) + ln];
            float wk2 = w2q[(((i << 2) + 2) << 6) + ln];
            float wk3 = w2q[(((i << 2) + 3) << 6) + ln];
            xp0 = fmaf(h0.x, wk0, xp0); xp1 = fmaf(h1.x, wk0, xp1);
            xp2 = fmaf(h2.x, wk0, xp2); xp3 = fmaf(h3.x, wk0, xp3);
            xp0 = fmaf(h0.y, wk1, xp0); xp1 = fmaf(h1.y, wk1, xp1);
            xp2 = fmaf(h2.y, wk1, xp2); xp3 = fmaf(h3.y, wk1, xp3);
            xp0 = fmaf(h0.z, wk2, xp0); xp1 = fmaf(h1.z, wk2, xp1);
            xp2 = fmaf(h2.z, wk2, xp2); xp3 = fmaf(h3.z, wk2, xp3);
            xp0 = fmaf(h0.w, wk3, xp0); xp1 = fmaf(h1.w, wk3, xp1);
            xp2 = fmaf(h2.w, wk3, xp2); xp3 = fmaf(h3.w, wk3, xp3);
        }
        sXp[wv][0][ln] = xp0; sXp[wv][1][ln] = xp1;
        sXp[wv][2][ln] = xp2; sXp[wv][3][ln] = xp3;
    }
    __syncthreads();

    {
        float Xf = sXp[0][wv][ln] + sXp[1][wv][ln]
                 + sXp[2][wv][ln] + sXp[3][wv][ln] + 66.0f * b2[ln];
        sX[wv][ln] = Xf;
    }
    __syncthreads();

    // ---- phase 3: h2[r][h] = relu(sum_o X[r][o] rw1[o][h] + rb1[h]) ----
    float c0, c1, c2, c3;
    c0 = c1 = c2 = c3 = rb1[tid];
    #pragma unroll 2
    for (int i = 0; i < 16; i++) {
        float4 X0 = ((const float4*)sX[0])[i];
        float4 X1 = ((const float4*)sX[1])[i];
        float4 X2 = ((const float4*)sX[2])[i];
        float4 X3 = ((const float4*)sX[3])[i];
        float r0 = rw1[(((i << 2) + 0) << 8) + tid];
        float r1 = rw1[(((i << 2) + 1) << 8) + tid];
        float r2 = rw1[(((i << 2) + 2) << 8) + tid];
        float r3 = rw1[(((i << 2) + 3) << 8) + tid];
        c0 = fmaf(X0.x, r0, c0); c1 = fmaf(X1.x, r0, c1);
        c2 = fmaf(X2.x, r0, c2); c3 = fmaf(X3.x, r0, c3);
        c0 = fmaf(X0.y, r1, c0); c1 = fmaf(X1.y, r1, c1);
        c2 = fmaf(X2.y, r1, c2); c3 = fmaf(X3.y, r1, c3);
        c0 = fmaf(X0.z, r2, c0); c1 = fmaf(X1.z, r2, c1);
        c2 = fmaf(X2.z, r2, c2); c3 = fmaf(X3.z, r2, c3);
        c0 = fmaf(X0.w, r3, c0); c1 = fmaf(X1.w, r3, c1);
        c2 = fmaf(X2.w, r3, c2); c3 = fmaf(X3.w, r3, c3);
    }
    c0 = fmaxf(c0, 0.f); c1 = fmaxf(c1, 0.f);
    c2 = fmaxf(c2, 0.f); c3 = fmaxf(c3, 0.f);

    // ---- phase 4: pre[r][c] = sum_h h2[r][h] rw2[h][c]; butterfly over h ----
    {
        float2 r2v = ((const float2*)rw2)[tid];
        float p00 = c0 * r2v.x, p01 = c0 * r2v.y;
        float p10 = c1 * r2v.x, p11 = c1 * r2v.y;
        float p20 = c2 * r2v.x, p21 = c2 * r2v.y;
        float p30 = c3 * r2v.x, p31 = c3 * r2v.y;
        #pragma unroll
        for (int m = 32; m >= 1; m >>= 1) {
            p00 += __shfl_xor(p00, m); p01 += __shfl_xor(p01, m);
            p10 += __shfl_xor(p10, m); p11 += __shfl_xor(p11, m);
            p20 += __shfl_xor(p20, m); p21 += __shfl_xor(p21, m);
            p30 += __shfl_xor(p30, m); p31 += __shfl_xor(p31, m);
        }
        if (ln == 0) {
            sP4[wv][0][0] = p00; sP4[wv][0][1] = p01;
            sP4[wv][1][0] = p10; sP4[wv][1][1] = p11;
            sP4[wv][2][0] = p20; sP4[wv][2][1] = p21;
            sP4[wv][3][0] = p30; sP4[wv][3][1] = p31;
        }
    }
    __syncthreads();

    if (tid < 8) {
        int r = tid >> 1, c = tid & 1;
        float pre = sP4[0][r][c] + sP4[1][r][c] + sP4[2][r][c] + sP4[3][r][c] + rb2[c];
        float a = 2.0f * tanhf(pre) + sbar[r][c];
        out[b0 * 2 + tid] = a;
        sa[tid] = a;
    }
    __syncthreads();
    // No global atomic: block max -> distinct slot (plain store).
    if (tid == 0) {
        float m = sa[0];
        #pragma unroll
        for (int i = 1; i < 8; i++) m = fmaxf(m, sa[i]);
        blkmax[blockIdx.x] = m;
    }
}

// ---- K2: reduce 1024 block maxima (L2-hot) + conditional rescale ----
__global__ __launch_bounds__(256) void bn_scale(
    float* __restrict__ out, const float* __restrict__ blkmax)
{
    __shared__ float sm[4];
    const int tid = threadIdx.x;
    const int ln  = tid & 63;
    const int wv  = tid >> 6;

    float m = fmaxf(fmaxf(blkmax[tid], blkmax[tid + 256]),
                    fmaxf(blkmax[tid + 512], blkmax[tid + 768]));
    #pragma unroll
    for (int s = 32; s >= 1; s >>= 1) m = fmaxf(m, __shfl_xor(m, s));
    if (ln == 0) sm[wv] = m;
    __syncthreads();
    float amax = fmaxf(fmaxf(sm[0], sm[1]), fmaxf(sm[2], sm[3]));

    float scale = 2.0f / amax;
    int i = blockIdx.x * 256 + tid;
    float a = out[i];
    out[i] = (scale < 1.0f) ? a * scale : a;
}

extern "C" void kernel_launch(void* const* d_in, const int* in_sizes, int n_in,
                              void* d_out, int out_size, void* d_ws, size_t ws_size,
                              hipStream_t stream) {
    const float* x   = (const float*)d_in[0];
    const float* w1  = (const float*)d_in[1];
    const float* b1  = (const float*)d_in[2];
    const float* w2  = (const float*)d_in[3];
    const float* b2  = (const float*)d_in[4];
    const float* rw1 = (const float*)d_in[5];
    const float* rb1 = (const float*)d_in[6];
    const float* rw2 = (const float*)d_in[7];
    const float* rb2 = (const float*)d_in[8];
    float* out = (float*)d_out;
    float* blkmax = (float*)d_ws;   // 1024 distinct slots, no init needed

    bn_row<<<NBLK, 256, 0, stream>>>(x, w1, b1, w2, b2, rw1, rb1, rw2, rb2,
                                     out, blkmax);
    bn_scale<<<8192 / 256, 256, 0, stream>>>(out, blkmax);
}